// Round 1
// baseline (131.257 us; speedup 1.0000x reference)
//
#include <hip/hip_runtime.h>
#include <cstddef>

#define T_LEN 4096
#define BATCH 4
#define HID   1024
#define NS    16
#define ROWS  (BATCH*T_LEN)   // 16384
#define CHUNK 64
#define NCH   (T_LEN/CHUNK)   // 64

// workspace float offsets
#define OFF_AD   0        // A_d            [16][16]
#define OFF_ADP  256      // A_d^64         [16][16]
#define OFF_X    512      // X = A^-1(Ad-I) [16][16]
#define OFF_BD   1024     // B_d            [16][1024]
#define OFF_U    32768    // u / states     [16384][16]
#define OFF_LEND 294912   // local-end      [4][64][16]
#define OFF_CIN  299008   // carry-in       [4][64][16]

// ---------------- setup: dt, A_d = expm(A*dt), X = A^-1 (A_d - I), A_d^64 ----
__global__ __launch_bounds__(256) void setup_kernel(const float* __restrict__ A,
                                                    const float* __restrict__ log_dt,
                                                    float* __restrict__ ws) {
    __shared__ float red[256];
    __shared__ float Ms[256], term[256], acc[256], AdL[256];
    __shared__ float aug[16*33];
    __shared__ float fr[16];
    __shared__ int   pivs;
    __shared__ float dts;
    const int tid = threadIdx.x;

    // dt = mean(exp(log_dt))
    float s = 0.f;
    for (int i = tid; i < HID; i += 256) s += expf(log_dt[i]);
    red[tid] = s;
    __syncthreads();
    for (int w = 128; w > 0; w >>= 1) {
        if (tid < w) red[tid] += red[tid + w];
        __syncthreads();
    }
    if (tid == 0) dts = red[0] * (1.f/1024.f);
    __syncthreads();
    const float dt = dts;

    const int r = tid >> 4, c = tid & 15;
    Ms[tid] = A[tid] * dt * (1.f/64.f);
    const float ident = (r == c) ? 1.f : 0.f;
    term[tid] = ident;
    acc[tid]  = ident;
    __syncthreads();

    // Taylor 12 on scaled matrix
    for (int i = 1; i <= 12; ++i) {
        float v = 0.f;
        #pragma unroll
        for (int m = 0; m < NS; ++m) v += term[r*16+m] * Ms[m*16+c];
        v /= (float)i;
        __syncthreads();
        term[tid] = v;
        acc[tid] += v;
        __syncthreads();
    }
    // 6 squarings -> A_d
    for (int sq = 0; sq < 6; ++sq) {
        float v = 0.f;
        #pragma unroll
        for (int m = 0; m < NS; ++m) v += acc[r*16+m] * acc[m*16+c];
        __syncthreads();
        acc[tid] = v;
        __syncthreads();
    }
    AdL[tid] = acc[tid];
    ws[OFF_AD + tid] = acc[tid];
    // 6 more squarings -> A_d^64 (chunk carry matrix)
    for (int sq = 0; sq < 6; ++sq) {
        float v = 0.f;
        #pragma unroll
        for (int m = 0; m < NS; ++m) v += acc[r*16+m] * acc[m*16+c];
        __syncthreads();
        acc[tid] = v;
        __syncthreads();
    }
    ws[OFF_ADP + tid] = acc[tid];

    // Gaussian elimination with partial pivoting: A * X = (A_d - I)
    for (int e = tid; e < 16*33; e += 256) {
        int rr = e / 33, cc = e % 33;
        float v;
        if (cc < 16)       v = A[rr*16+cc];
        else if (cc < 32)  { int k = cc-16; v = AdL[rr*16+k] - ((rr==k)?1.f:0.f); }
        else               v = 0.f;
        aug[e] = v;
    }
    __syncthreads();
    for (int k = 0; k < 16; ++k) {
        if (tid == 0) {
            int p = k; float best = fabsf(aug[k*33+k]);
            for (int i = k+1; i < 16; ++i) {
                float a = fabsf(aug[i*33+k]);
                if (a > best) { best = a; p = i; }
            }
            pivs = p;
        }
        __syncthreads();
        const int p = pivs;
        if (p != k && tid < 33) {
            float t1 = aug[k*33+tid]; aug[k*33+tid] = aug[p*33+tid]; aug[p*33+tid] = t1;
        }
        __syncthreads();
        if (tid > k && tid < 16) fr[tid] = aug[tid*33+k] / aug[k*33+k];
        __syncthreads();
        const int nr = 15 - k;
        for (int e = tid; e < nr*33; ++e) {
            // strided loop
            break;
        }
        for (int e = tid; e < nr*33; e += 256) {
            int i = k + 1 + e / 33, cc = e % 33;
            aug[i*33+cc] -= fr[i] * aug[k*33+cc];
        }
        __syncthreads();
    }
    if (tid < 16) {
        const int cc = tid;
        float xc[16];
        #pragma unroll
        for (int i = 15; i >= 0; --i) {
            float sv = aug[i*33+16+cc];
            #pragma unroll
            for (int j = 15; j > i; --j) sv -= aug[i*33+j] * xc[j];
            xc[i] = sv / aug[i*33+i];
        }
        #pragma unroll
        for (int i = 0; i < 16; ++i) ws[OFF_X + i*16 + cc] = xc[i];
    }
}

// ---------------- B_d = X @ B  [16][1024] --------------------------------
__global__ __launch_bounds__(256) void bd_kernel(const float* __restrict__ B,
                                                 float* __restrict__ ws) {
    __shared__ float Xs[256];
    const int tid = threadIdx.x;
    Xs[tid] = ws[OFF_X + tid];
    __syncthreads();
    const int idx = blockIdx.x * 256 + tid;   // 0..16383
    const int n = idx >> 10, h = idx & 1023;
    float a = 0.f;
    #pragma unroll
    for (int m = 0; m < NS; ++m) a += Xs[n*16+m] * B[m*HID + h];
    ws[OFF_BD + n*HID + h] = a;
}

// ---------------- u[row][n] = sum_h x[row][h] * B_d[n][h] ----------------
__global__ __launch_bounds__(256) void u_kernel(const float* __restrict__ x,
                                                float* __restrict__ ws) {
    __shared__ float xs[32*260];
    __shared__ float bds[16*260];
    const int tid = threadIdx.x;
    const int r  = tid >> 3;      // 0..31
    const int n0 = tid & 7;       // 0..7
    const int row0 = blockIdx.x * 32;
    float acc0 = 0.f, acc1 = 0.f;

    for (int kc = 0; kc < HID; kc += 256) {
        #pragma unroll
        for (int j = 0; j < 8; ++j) {
            int f = tid + 256*j;           // float4 id over 32x256 tile
            int rr = f >> 6; int col = (f & 63) << 2;
            float4 v = *(const float4*)(x + (size_t)(row0+rr)*HID + kc + col);
            *(float4*)(xs + rr*260 + col) = v;
        }
        #pragma unroll
        for (int j = 0; j < 4; ++j) {
            int f = tid + 256*j;           // float4 id over 16x256 tile
            int nn = f >> 6; int col = (f & 63) << 2;
            float4 v = *(const float4*)(ws + OFF_BD + (size_t)nn*HID + kc + col);
            *(float4*)(bds + nn*260 + col) = v;
        }
        __syncthreads();
        #pragma unroll 8
        for (int h = 0; h < 256; h += 4) {
            float4 xv = *(const float4*)(xs + r*260 + h);
            float4 av = *(const float4*)(bds + n0*260 + h);
            float4 bv = *(const float4*)(bds + (n0+8)*260 + h);
            acc0 += xv.x*av.x + xv.y*av.y + xv.z*av.z + xv.w*av.w;
            acc1 += xv.x*bv.x + xv.y*bv.y + xv.z*bv.z + xv.w*bv.w;
        }
        __syncthreads();
    }
    ws[OFF_U + (size_t)(row0+r)*16 + n0]     = acc0;
    ws[OFF_U + (size_t)(row0+r)*16 + n0 + 8] = acc1;
}

// ---------------- scan phase 1: local scans per (batch, chunk) -----------
__global__ __launch_bounds__(256) void scan1_kernel(float* __restrict__ ws) {
    const int tid = threadIdx.x;
    const int wave = tid >> 6, lane = tid & 63;
    const int w = blockIdx.x * 4 + wave;          // 0..63
    const int pid = w * 4 + (lane >> 4);          // 0..255 (b,chunk) pair
    const int b = pid >> 6, cch = pid & 63;
    const int n = lane & 15;
    const int rowbase = b*T_LEN + cch*CHUNK;

    float Acol[16];
    #pragma unroll
    for (int m = 0; m < NS; ++m) Acol[m] = ws[OFF_AD + m*16 + n];

    float v = 0.f;
    for (int t = 0; t < CHUNK; ++t) {
        const int addr = OFF_U + (rowbase + t)*16 + n;
        float nv = ws[addr];
        #pragma unroll
        for (int m = 0; m < NS; ++m) nv += __shfl(v, m, 16) * Acol[m];
        v = nv;
        ws[addr] = v;
    }
    ws[OFF_LEND + (b*NCH + cch)*16 + n] = v;
}

// ---------------- scan phase 2: sequential carry over chunks -------------
__global__ __launch_bounds__(64) void scan2_kernel(const float* __restrict__ state,
                                                   float* __restrict__ ws,
                                                   float* __restrict__ out) {
    const int lane = threadIdx.x;
    const int b = lane >> 4, n = lane & 15;
    float Pcol[16];
    #pragma unroll
    for (int m = 0; m < NS; ++m) Pcol[m] = ws[OFF_ADP + m*16 + n];

    float v = state[b*16 + n];
    for (int cch = 0; cch < NCH; ++cch) {
        ws[OFF_CIN + (b*NCH + cch)*16 + n] = v;
        float nv = ws[OFF_LEND + (b*NCH + cch)*16 + n];
        #pragma unroll
        for (int m = 0; m < NS; ++m) nv += __shfl(v, m, 16) * Pcol[m];
        v = nv;
    }
    out[(size_t)ROWS*HID + b*16 + n] = v;   // final_state
}

// ---------------- scan phase 3: add carry propagation --------------------
__global__ __launch_bounds__(256) void scan3_kernel(float* __restrict__ ws) {
    const int tid = threadIdx.x;
    const int wave = tid >> 6, lane = tid & 63;
    const int w = blockIdx.x * 4 + wave;
    const int pid = w * 4 + (lane >> 4);
    const int b = pid >> 6, cch = pid & 63;
    const int n = lane & 15;
    const int rowbase = b*T_LEN + cch*CHUNK;

    float Acol[16];
    #pragma unroll
    for (int m = 0; m < NS; ++m) Acol[m] = ws[OFF_AD + m*16 + n];

    float v = ws[OFF_CIN + (b*NCH + cch)*16 + n];
    for (int t = 0; t < CHUNK; ++t) {
        float nv = 0.f;
        #pragma unroll
        for (int m = 0; m < NS; ++m) nv += __shfl(v, m, 16) * Acol[m];
        v = nv;
        const int addr = OFF_U + (rowbase + t)*16 + n;
        ws[addr] = ws[addr] + v;
    }
}

// ---------------- out[row][h] = sum_n states[row][n] * C[h][n] -----------
__global__ __launch_bounds__(256) void out_kernel(const float* __restrict__ C,
                                                  const float* __restrict__ ws,
                                                  float* __restrict__ out) {
    __shared__ float st[64*16];
    const int tid = threadIdx.x;
    const int row0 = blockIdx.x * 64;

    float Creg[4][16];
    #pragma unroll
    for (int k = 0; k < 4; ++k) {
        #pragma unroll
        for (int q = 0; q < 4; ++q) {
            float4 cv = *(const float4*)(C + (size_t)(4*tid + k)*16 + 4*q);
            Creg[k][4*q+0] = cv.x; Creg[k][4*q+1] = cv.y;
            Creg[k][4*q+2] = cv.z; Creg[k][4*q+3] = cv.w;
        }
    }
    {   // stage 64 rows of states
        int f = tid;               // float4 id over 64x16
        int rr = f >> 2; int nn = (f & 3) << 2;
        *(float4*)(st + rr*16 + nn) =
            *(const float4*)(ws + OFF_U + (size_t)(row0+rr)*16 + nn);
    }
    __syncthreads();

    for (int rr = 0; rr < 64; ++rr) {
        float sv[16];
        #pragma unroll
        for (int q = 0; q < 4; ++q) {
            float4 s4 = *(const float4*)(st + rr*16 + 4*q);
            sv[4*q+0] = s4.x; sv[4*q+1] = s4.y; sv[4*q+2] = s4.z; sv[4*q+3] = s4.w;
        }
        float4 o;
        float ov[4];
        #pragma unroll
        for (int k = 0; k < 4; ++k) {
            float a = 0.f;
            #pragma unroll
            for (int n = 0; n < NS; ++n) a += sv[n] * Creg[k][n];
            ov[k] = a;
        }
        o.x = ov[0]; o.y = ov[1]; o.z = ov[2]; o.w = ov[3];
        *(float4*)(out + (size_t)(row0+rr)*HID + 4*tid) = o;
    }
}

extern "C" void kernel_launch(void* const* d_in, const int* in_sizes, int n_in,
                              void* d_out, int out_size, void* d_ws, size_t ws_size,
                              hipStream_t stream) {
    const float* x      = (const float*)d_in[0];
    const float* state  = (const float*)d_in[1];
    const float* A      = (const float*)d_in[2];
    const float* B      = (const float*)d_in[3];
    const float* C      = (const float*)d_in[4];
    const float* log_dt = (const float*)d_in[5];
    float* out = (float*)d_out;
    float* ws  = (float*)d_ws;

    setup_kernel<<<1, 256, 0, stream>>>(A, log_dt, ws);
    bd_kernel  <<<64, 256, 0, stream>>>(B, ws);
    u_kernel   <<<ROWS/32, 256, 0, stream>>>(x, ws);
    scan1_kernel<<<16, 256, 0, stream>>>(ws);
    scan2_kernel<<<1, 64, 0, stream>>>(state, ws, out);
    scan3_kernel<<<16, 256, 0, stream>>>(ws);
    out_kernel <<<ROWS/64, 256, 0, stream>>>(C, ws, out);
}

// Round 2
// 97.881 us; speedup vs baseline: 1.3410x; 1.3410x over previous
//
#include <hip/hip_runtime.h>
#include <cstddef>

#define T_LEN 4096
#define BATCH 4
#define HID   1024
#define NS    16
#define ROWS  (BATCH*T_LEN)   // 16384
#define CHUNK 64
#define NCH   (T_LEN/CHUNK)   // 64

// workspace float offsets
#define OFF_AD   0        // A_d               [16][16]
#define OFF_X    512      // dt*phi1(A dt)     [16][16]
#define OFF_P    1024     // P_k = A_d^k, k=1..64  [64][16][16]
#define OFF_BD   20480    // B_d               [16][1024]
#define OFF_U    40960    // local states      [16384][16]
#define OFF_LEND 303104   // chunk-end local states [4][64][16]
#define OFF_CIN  307200   // carry-in per chunk     [4][64][16]

// ---------- setup: dt, A_d = expm(A dt), G = phi1, powers P_1..P_64 ----------
__global__ __launch_bounds__(256) void setup_kernel(const float* __restrict__ A,
                                                    const float* __restrict__ log_dt,
                                                    float* __restrict__ ws) {
    __shared__ float red[256];
    __shared__ float Ms[256], term[256], E[256], G[256];
    __shared__ float Pl[64*256];   // 64 KB: Pl[k] = A_d^{k+1}
    const int tid = threadIdx.x;

    // dt = mean(exp(log_dt))
    float s = 0.f;
    for (int i = tid; i < HID; i += 256) s += expf(log_dt[i]);
    red[tid] = s;
    __syncthreads();
    for (int w = 128; w > 0; w >>= 1) {
        if (tid < w) red[tid] += red[tid + w];
        __syncthreads();
    }
    const float dt = red[0] * (1.f/1024.f);

    const int r = tid >> 4, c = tid & 15;
    const float ident = (r == c) ? 1.f : 0.f;
    Ms[tid]   = A[tid] * (dt * (1.f/64.f));
    term[tid] = ident;
    E[tid]    = ident;   // expm Taylor accumulator
    G[tid]    = ident;   // phi1 Taylor accumulator (j=0 term)
    __syncthreads();

    // Taylor: term_i = Ms^i / i!;  E += term;  G += term/(i+1)
    for (int i = 1; i <= 12; ++i) {
        float v = 0.f;
        #pragma unroll
        for (int m = 0; m < NS; ++m) v += term[r*16+m] * Ms[m*16+c];
        v /= (float)i;
        __syncthreads();
        term[tid] = v;
        E[tid] += v;
        G[tid] += v * (1.f/(float)(i+1));
        __syncthreads();
    }
    // 6 doublings: G <- 0.5*G*(E+I); E <- E*E   (old E in both)
    for (int d = 0; d < 6; ++d) {
        float ge = 0.f, ee = 0.f;
        #pragma unroll
        for (int m = 0; m < NS; ++m) {
            ge += G[r*16+m] * (E[m*16+c] + ((m==c)?1.f:0.f));
            ee += E[r*16+m] * E[m*16+c];
        }
        __syncthreads();
        G[tid] = 0.5f * ge;
        E[tid] = ee;
        __syncthreads();
    }
    ws[OFF_AD + tid] = E[tid];        // A_d
    ws[OFF_X  + tid] = dt * G[tid];   // dt*phi1 = A^-1(A_d - I)
    Pl[tid] = E[tid];                 // P_1
    __syncthreads();
    // powers by doubling: P_{pm+j+1} = P_{j+1} * P_{pm}
    for (int pm = 1; pm < 64; pm <<= 1) {
        for (int idx = tid; idx < pm*256; idx += 256) {
            const int j = idx >> 8, e = idx & 255, rr = e >> 4, cc = e & 15;
            float v = 0.f;
            #pragma unroll
            for (int m = 0; m < NS; ++m)
                v += Pl[j*256 + rr*16 + m] * Pl[(pm-1)*256 + m*16 + cc];
            Pl[(pm + j)*256 + e] = v;
        }
        __syncthreads();
    }
    for (int i = tid*4; i < 64*256; i += 1024)
        *(float4*)(ws + OFF_P + i) = *(const float4*)(&Pl[i]);
}

// ---------- B_d = (dt*phi1) @ B   [16][1024] ----------
__global__ __launch_bounds__(256) void bd_kernel(const float* __restrict__ B,
                                                 float* __restrict__ ws) {
    __shared__ float Xs[256];
    const int tid = threadIdx.x;
    Xs[tid] = ws[OFF_X + tid];
    __syncthreads();
    const int idx = blockIdx.x * 256 + tid;   // 0..16383
    const int n = idx >> 10, h = idx & 1023;
    float a = 0.f;
    #pragma unroll
    for (int m = 0; m < NS; ++m) a += Xs[n*16+m] * B[m*HID + h];
    ws[OFF_BD + n*HID + h] = a;
}

// ---------- K1: u = x @ B_d^T fused with local chunk scan ----------
// block = one chunk = 64 rows; 256 threads = 16 rowgroups(4 rows) x 16 n
__global__ __launch_bounds__(256) void k1_kernel(const float* __restrict__ x,
                                                 float* __restrict__ ws) {
    __shared__ __align__(16) float xs[32*68];     // xs[h][row], transposed, stride 68
    __shared__ __align__(16) float bds[16*36];    // bds[n][h], stride 36
    __shared__ __align__(16) float us[64*16];     // u -> local states
    const int tid = threadIdx.x;
    const int ng = tid & 15;          // n
    const int rg = tid >> 4;          // 0..15 -> rows 4rg..4rg+3
    const int row0 = blockIdx.x * 64;

    const int srow0 = tid >> 3;          // staging row (0..31)
    const int sc4   = (tid & 7) * 4;     // staging col within 32-chunk
    const int srow1 = srow0 + 32;
    const int bn    = tid >> 3;          // bds n for tid<128
    const int bc4   = (tid & 7) * 4;

    const float* xp0 = x + (size_t)(row0 + srow0)*HID + sc4;
    const float* xp1 = x + (size_t)(row0 + srow1)*HID + sc4;
    const float* bdp = ws + OFF_BD + (size_t)bn*HID + bc4;

    // depth-2 register prefetch
    float4 xa0 = *(const float4*)(xp0);
    float4 xa1 = *(const float4*)(xp1);
    float4 xb0 = *(const float4*)(xp0 + 32);
    float4 xb1 = *(const float4*)(xp1 + 32);
    float4 ba, bb;
    if (tid < 128) { ba = *(const float4*)(bdp); bb = *(const float4*)(bdp + 32); }

    float acc0=0.f, acc1=0.f, acc2=0.f, acc3=0.f;

    for (int kc = 0; kc < 32; ++kc) {
        // stage current chunk (transpose x into xs[h][row])
        xs[(sc4+0)*68 + srow0] = xa0.x;
        xs[(sc4+1)*68 + srow0] = xa0.y;
        xs[(sc4+2)*68 + srow0] = xa0.z;
        xs[(sc4+3)*68 + srow0] = xa0.w;
        xs[(sc4+0)*68 + srow1] = xa1.x;
        xs[(sc4+1)*68 + srow1] = xa1.y;
        xs[(sc4+2)*68 + srow1] = xa1.z;
        xs[(sc4+3)*68 + srow1] = xa1.w;
        if (tid < 128) *(float4*)(&bds[bn*36 + bc4]) = ba;
        __syncthreads();
        // rotate prefetch regs, issue loads 2 chunks ahead
        xa0 = xb0; xa1 = xb1; ba = bb;
        if (kc + 2 < 32) {
            const int off = (kc + 2) * 32;
            xb0 = *(const float4*)(xp0 + off);
            xb1 = *(const float4*)(xp1 + off);
            if (tid < 128) bb = *(const float4*)(bdp + off);
        }
        // compute: 4 rows x 1 n per thread
        const float* bp = &bds[ng*36];
        const float* xq = &xs[4*rg];
        #pragma unroll
        for (int hg = 0; hg < 8; ++hg) {
            const int h0 = hg*4;
            float4 bv = *(const float4*)(bp + h0);
            float4 x0 = *(const float4*)(xq + (h0+0)*68);
            float4 x1 = *(const float4*)(xq + (h0+1)*68);
            float4 x2 = *(const float4*)(xq + (h0+2)*68);
            float4 x3 = *(const float4*)(xq + (h0+3)*68);
            acc0 += x0.x*bv.x + x1.x*bv.y + x2.x*bv.z + x3.x*bv.w;
            acc1 += x0.y*bv.x + x1.y*bv.y + x2.y*bv.z + x3.y*bv.w;
            acc2 += x0.z*bv.x + x1.z*bv.y + x2.z*bv.z + x3.z*bv.w;
            acc3 += x0.w*bv.x + x1.w*bv.y + x2.w*bv.z + x3.w*bv.w;
        }
        __syncthreads();
    }
    us[(4*rg+0)*16 + ng] = acc0;
    us[(4*rg+1)*16 + ng] = acc1;
    us[(4*rg+2)*16 + ng] = acc2;
    us[(4*rg+3)*16 + ng] = acc3;
    __syncthreads();

    // local scan: 64 steps, wave 0, m-split 4-way across mg
    if (tid < 64) {
        const int n = tid & 15, mg = tid >> 4;
        const float a0 = ws[OFF_AD + (mg*4+0)*16 + n];
        const float a1 = ws[OFF_AD + (mg*4+1)*16 + n];
        const float a2 = ws[OFF_AD + (mg*4+2)*16 + n];
        const float a3 = ws[OFF_AD + (mg*4+3)*16 + n];
        float v = 0.f;
        for (int t = 0; t < 64; ++t) {
            const float u0 = us[t*16 + n];
            float q = __shfl(v, mg*4+0, 16)*a0 + __shfl(v, mg*4+1, 16)*a1
                    + __shfl(v, mg*4+2, 16)*a2 + __shfl(v, mg*4+3, 16)*a3;
            q += __shfl_xor(q, 16);
            q += __shfl_xor(q, 32);
            v = u0 + q;                    // replicated across mg
            if (mg == 0) us[t*16 + n] = v;
        }
        if (mg == 0) {
            const int b = row0 >> 12, cch = (row0 >> 6) & 63;
            ws[OFF_LEND + (b*NCH + cch)*16 + n] = v;
        }
    }
    __syncthreads();
    {
        const int j = tid >> 2, n4 = (tid & 3)*4;
        *(float4*)(ws + OFF_U + (size_t)(row0 + j)*16 + n4) = *(const float4*)(&us[j*16 + n4]);
    }
}

// ---------- scan2: carry across chunks, register-resident ----------
// 1 block, 256 threads; wave = batch b; lane = n + 16*mg
__global__ __launch_bounds__(256) void scan2_kernel(const float* __restrict__ state,
                                                    float* __restrict__ ws,
                                                    float* __restrict__ out) {
    const int tid = threadIdx.x;
    const int b = tid >> 6;
    const int lane = tid & 63;
    const int n = lane & 15, mg = lane >> 4;
    const float p0 = ws[OFF_P + 63*256 + (mg*4+0)*16 + n];   // P_64
    const float p1 = ws[OFF_P + 63*256 + (mg*4+1)*16 + n];
    const float p2 = ws[OFF_P + 63*256 + (mg*4+2)*16 + n];
    const float p3 = ws[OFF_P + 63*256 + (mg*4+3)*16 + n];
    float le[NCH];
    #pragma unroll
    for (int c = 0; c < NCH; ++c) le[c] = ws[OFF_LEND + (b*NCH + c)*16 + n];
    float v = state[b*16 + n];
    #pragma unroll
    for (int c = 0; c < NCH; ++c) {
        if (mg == 0) ws[OFF_CIN + (b*NCH + c)*16 + n] = v;
        float q = __shfl(v, mg*4+0, 16)*p0 + __shfl(v, mg*4+1, 16)*p1
                + __shfl(v, mg*4+2, 16)*p2 + __shfl(v, mg*4+3, 16)*p3;
        q += __shfl_xor(q, 16);
        q += __shfl_xor(q, 32);
        v = le[c] + q;
    }
    if (mg == 0) out[(size_t)ROWS*HID + b*16 + n] = v;   // final_state
}

// ---------- K2: states = local + P_{j+1}*cin, then out = states @ C^T ----------
// block = one chunk = 64 rows; 256 threads
__global__ __launch_bounds__(256) void k2_kernel(const float* __restrict__ C,
                                                 const float* __restrict__ ws,
                                                 float* __restrict__ out) {
    __shared__ __align__(16) float st[64*16];
    __shared__ float cin_s[16];
    const int tid = threadIdx.x;
    const int row0 = blockIdx.x * 64;
    const int b = row0 >> 12, cch = (row0 >> 6) & 63;

    if (tid < 16) cin_s[tid] = ws[OFF_CIN + (b*NCH + cch)*16 + tid];

    float Creg[4][16];
    #pragma unroll
    for (int k = 0; k < 4; ++k) {
        #pragma unroll
        for (int q = 0; q < 4; ++q) {
            float4 cv = *(const float4*)(C + (size_t)(4*tid + k)*16 + 4*q);
            Creg[k][4*q+0] = cv.x; Creg[k][4*q+1] = cv.y;
            Creg[k][4*q+2] = cv.z; Creg[k][4*q+3] = cv.w;
        }
    }
    __syncthreads();
    {
        const int j = tid >> 2, n4 = (tid & 3)*4;
        float4 ls = *(const float4*)(ws + OFF_U + (size_t)(row0 + j)*16 + n4);
        const float* P = ws + OFF_P + j*256 + n4;   // P_{j+1}
        float cx=0.f, cy=0.f, cz=0.f, cw=0.f;
        #pragma unroll
        for (int m = 0; m < NS; ++m) {
            const float cm = cin_s[m];
            float4 pv = *(const float4*)(P + m*16);
            cx += cm*pv.x; cy += cm*pv.y; cz += cm*pv.z; cw += cm*pv.w;
        }
        *(float4*)(&st[j*16 + n4]) = make_float4(ls.x+cx, ls.y+cy, ls.z+cz, ls.w+cw);
    }
    __syncthreads();
    for (int rr = 0; rr < 64; ++rr) {
        float sv[16];
        #pragma unroll
        for (int q = 0; q < 4; ++q) {
            float4 s4 = *(const float4*)(&st[rr*16 + 4*q]);
            sv[4*q+0]=s4.x; sv[4*q+1]=s4.y; sv[4*q+2]=s4.z; sv[4*q+3]=s4.w;
        }
        float ov[4];
        #pragma unroll
        for (int k = 0; k < 4; ++k) {
            float a = 0.f;
            #pragma unroll
            for (int nn = 0; nn < NS; ++nn) a += sv[nn] * Creg[k][nn];
            ov[k] = a;
        }
        *(float4*)(out + (size_t)(row0+rr)*HID + 4*tid) = make_float4(ov[0],ov[1],ov[2],ov[3]);
    }
}

extern "C" void kernel_launch(void* const* d_in, const int* in_sizes, int n_in,
                              void* d_out, int out_size, void* d_ws, size_t ws_size,
                              hipStream_t stream) {
    const float* x      = (const float*)d_in[0];
    const float* state  = (const float*)d_in[1];
    const float* A      = (const float*)d_in[2];
    const float* B      = (const float*)d_in[3];
    const float* C      = (const float*)d_in[4];
    const float* log_dt = (const float*)d_in[5];
    float* out = (float*)d_out;
    float* ws  = (float*)d_ws;

    setup_kernel<<<1, 256, 0, stream>>>(A, log_dt, ws);
    bd_kernel   <<<64, 256, 0, stream>>>(B, ws);
    k1_kernel   <<<256, 256, 0, stream>>>(x, ws);
    scan2_kernel<<<1, 256, 0, stream>>>(state, ws, out);
    k2_kernel   <<<256, 256, 0, stream>>>(C, ws, out);
}